// Round 1
// baseline (708.494 us; speedup 1.0000x reference)
//
#include <hip/hip_runtime.h>

// ---------- bf16 helpers (manual, keep everything as ushort) ----------
__device__ __forceinline__ unsigned short f2bf(float f) {
    unsigned u = __float_as_uint(f);
    u += 0x7fffu + ((u >> 16) & 1u);   // round-to-nearest-even
    return (unsigned short)(u >> 16);
}
__device__ __forceinline__ float bf2f(unsigned short b) {
    return __uint_as_float((unsigned)b << 16);
}
__device__ __forceinline__ float bflo(unsigned u) { return __uint_as_float(u << 16); }
__device__ __forceinline__ float bfhi(unsigned u) { return __uint_as_float(u & 0xffff0000u); }

// ---------- degree count ----------
__global__ __launch_bounds__(256) void k_deg(const int* __restrict__ dst, int E,
                                             int* __restrict__ deg) {
    int i = blockIdx.x * 256 + threadIdx.x;
    if (i < E) atomicAdd(&deg[dst[i]], 1);
}

// ---------- dinv = rsqrt(deg + 1 selfloop) ----------
__global__ __launch_bounds__(256) void k_dinv(const int* __restrict__ deg, int N,
                                              float* __restrict__ dinv) {
    int i = blockIdx.x * 256 + threadIdx.x;
    if (i < N) dinv[i] = rsqrtf((float)(deg[i] + 1));
}

// ---------- 3-kernel exclusive scan of deg -> rowptr (1024 elems / block) ----------
__global__ __launch_bounds__(256) void k_scan_part(const int* __restrict__ deg, int N,
                                                   int* __restrict__ part) {
    int base = blockIdx.x * 1024 + threadIdx.x * 4;
    int s = 0;
#pragma unroll
    for (int i = 0; i < 4; ++i) { int idx = base + i; if (idx < N) s += deg[idx]; }
    __shared__ int red[256];
    red[threadIdx.x] = s; __syncthreads();
    for (int off = 128; off > 0; off >>= 1) {
        if (threadIdx.x < off) red[threadIdx.x] += red[threadIdx.x + off];
        __syncthreads();
    }
    if (threadIdx.x == 0) part[blockIdx.x] = red[0];
}
__global__ void k_scan_mid(int* part, int nb) {
    if (threadIdx.x == 0 && blockIdx.x == 0) {
        int run = 0;
        for (int i = 0; i < nb; ++i) { int t = part[i]; part[i] = run; run += t; }
    }
}
__global__ __launch_bounds__(256) void k_scan_final(const int* __restrict__ deg, int N,
                                                    const int* __restrict__ part,
                                                    int* __restrict__ rowptr) {
    int t = threadIdx.x;
    int base = blockIdx.x * 1024 + t * 4;
    int v[4]; int s = 0;
#pragma unroll
    for (int i = 0; i < 4; ++i) { int idx = base + i; v[i] = (idx < N) ? deg[idx] : 0; s += v[i]; }
    __shared__ int sc[256];
    sc[t] = s; __syncthreads();
    for (int off = 1; off < 256; off <<= 1) {
        int x = (t >= off) ? sc[t - off] : 0;
        __syncthreads();
        sc[t] += x;
        __syncthreads();
    }
    int excl = sc[t] - s + part[blockIdx.x];
#pragma unroll
    for (int i = 0; i < 4; ++i) {
        int idx = base + i;
        if (idx < N) { rowptr[idx] = excl; excl += v[i]; }
    }
}

// ---------- CSR fill (order within a row is arbitrary; sum is what matters) ----------
__global__ __launch_bounds__(256) void k_fill(const int* __restrict__ src,
                                              const int* __restrict__ dst, int E,
                                              const int* __restrict__ rowptr,
                                              int* __restrict__ fill,
                                              const float* __restrict__ dinv,
                                              int* __restrict__ csr_s,
                                              float* __restrict__ csr_n) {
    int i = blockIdx.x * 256 + threadIdx.x;
    if (i >= E) return;
    int s = src[i], d = dst[i];
    int pos = rowptr[d] + atomicAdd(&fill[d], 1);
    csr_s[pos] = s;
    csr_n[pos] = dinv[s] * dinv[d];
}

// ---------- GEMM: H(bf16) = act(X) @ W ; act = optional BN(scale,shift)+ReLU ----------
// block: 256 thr; tile 64 rows x 128 cols; thread tile 8x4; W in LDS (bf16), X tile fp32
__global__ __launch_bounds__(256) void k_gemm(const float* __restrict__ X,
                                              const float* __restrict__ Wg,
                                              const float* __restrict__ scale,
                                              const float* __restrict__ shift,
                                              unsigned short* __restrict__ Hout,
                                              int N, int applyBN) {
    __shared__ unsigned short sW[128 * 128]; // 32 KB
    __shared__ float sX[64 * 128];           // 32 KB
    const int tid = threadIdx.x;
    const int rowBase = blockIdx.x * 64;

    // stage W -> bf16 LDS
    for (int i = tid * 4; i < 128 * 128; i += 1024) {
        float4 w4 = *(const float4*)&Wg[i];
        ushort4 p;
        p.x = f2bf(w4.x); p.y = f2bf(w4.y); p.z = f2bf(w4.z); p.w = f2bf(w4.w);
        *(ushort4*)&sW[i] = p;
    }
    // stage X tile (with optional BN+ReLU)
    for (int j = 0; j < 8; ++j) {
        int f4 = tid + 256 * j;          // 2048 float4s = 64 rows * 32
        int r = f4 >> 5;
        int k4 = (f4 & 31) * 4;
        int gr = rowBase + r;
        float4 v = make_float4(0.f, 0.f, 0.f, 0.f);
        if (gr < N) v = *(const float4*)&X[(size_t)gr * 128 + k4];
        if (applyBN) {
            v.x = fmaxf(fmaf(v.x, scale[k4 + 0], shift[k4 + 0]), 0.f);
            v.y = fmaxf(fmaf(v.y, scale[k4 + 1], shift[k4 + 1]), 0.f);
            v.z = fmaxf(fmaf(v.z, scale[k4 + 2], shift[k4 + 2]), 0.f);
            v.w = fmaxf(fmaf(v.w, scale[k4 + 3], shift[k4 + 3]), 0.f);
        }
        *(float4*)&sX[r * 128 + k4] = v;
    }
    __syncthreads();

    const int cg = tid & 31, rg = tid >> 5;
    const int c0 = cg * 4;
    const int r0 = rg * 8;
    float acc[8][4] = {};
#pragma unroll 4
    for (int k = 0; k < 128; ++k) {
        ushort4 wv = *(const ushort4*)&sW[k * 128 + c0];
        float w0 = bf2f(wv.x), w1 = bf2f(wv.y), w2 = bf2f(wv.z), w3 = bf2f(wv.w);
#pragma unroll
        for (int i = 0; i < 8; ++i) {
            float xv = sX[(r0 + i) * 128 + k];
            acc[i][0] = fmaf(xv, w0, acc[i][0]);
            acc[i][1] = fmaf(xv, w1, acc[i][1]);
            acc[i][2] = fmaf(xv, w2, acc[i][2]);
            acc[i][3] = fmaf(xv, w3, acc[i][3]);
        }
    }
#pragma unroll
    for (int i = 0; i < 8; ++i) {
        int gr = rowBase + r0 + i;
        if (gr < N) {
            ushort4 p;
            p.x = f2bf(acc[i][0]); p.y = f2bf(acc[i][1]);
            p.z = f2bf(acc[i][2]); p.w = f2bf(acc[i][3]);
            *(ushort4*)&Hout[(size_t)gr * 128 + c0] = p;
        }
    }
}

// ---------- aggregation: agg[n] = sum_{e: dst=n} norm_e * H[src_e] + dinv[n]^2*H[n] + bias
// one wave (64 lanes) per node, 2 features/lane, bf16 gather, fp32 accumulate
__global__ __launch_bounds__(256) void k_agg(const unsigned short* __restrict__ H,
                                             const int* __restrict__ rowptr,
                                             const int* __restrict__ deg,
                                             const int* __restrict__ csr_s,
                                             const float* __restrict__ csr_n,
                                             const float* __restrict__ dinv,
                                             const float* __restrict__ bias,
                                             float* __restrict__ out, int N) {
    int wave = threadIdx.x >> 6;
    int lane = threadIdx.x & 63;
    int node = blockIdx.x * 4 + wave;
    if (node >= N) return;
    const unsigned* Hu = (const unsigned*)H;
    int start = rowptr[node];
    int cnt = deg[node];
    int end = start + cnt;
    float a0 = 0.f, a1 = 0.f;
    int j = start;
    for (; j + 1 < end; j += 2) {
        int s0 = csr_s[j], s1 = csr_s[j + 1];
        float w0 = csr_n[j], w1 = csr_n[j + 1];
        unsigned u0 = Hu[(size_t)s0 * 64 + lane];
        unsigned u1 = Hu[(size_t)s1 * 64 + lane];
        a0 = fmaf(w0, bflo(u0), a0);
        a1 = fmaf(w0, bfhi(u0), a1);
        a0 = fmaf(w1, bflo(u1), a0);
        a1 = fmaf(w1, bfhi(u1), a1);
    }
    if (j < end) {
        int s0 = csr_s[j];
        float w0 = csr_n[j];
        unsigned u0 = Hu[(size_t)s0 * 64 + lane];
        a0 = fmaf(w0, bflo(u0), a0);
        a1 = fmaf(w0, bfhi(u0), a1);
    }
    { // self loop
        float dn = dinv[node];
        float w = dn * dn;
        unsigned u = Hu[(size_t)node * 64 + lane];
        a0 = fmaf(w, bflo(u), a0);
        a1 = fmaf(w, bfhi(u), a1);
    }
    a0 += bias[2 * lane];
    a1 += bias[2 * lane + 1];
    ((float2*)out)[(size_t)node * 64 + lane] = make_float2(a0, a1);
}

// ---------- BN column stats: S1 += sum, S2 += sum of squares ----------
__global__ __launch_bounds__(256) void k_stats(const float* __restrict__ A, int N,
                                               float* __restrict__ S1,
                                               float* __restrict__ S2) {
    int c = threadIdx.x & 127;
    int rh = threadIdx.x >> 7;
    float s1 = 0.f, s2 = 0.f;
    for (int r = blockIdx.x * 2 + rh; r < N; r += gridDim.x * 2) {
        float v = A[(size_t)r * 128 + c];
        s1 += v;
        s2 = fmaf(v, v, s2);
    }
    __shared__ float l1[256], l2[256];
    l1[threadIdx.x] = s1; l2[threadIdx.x] = s2;
    __syncthreads();
    if (rh == 0) {
        atomicAdd(&S1[c], s1 + l1[c + 128]);
        atomicAdd(&S2[c], s2 + l2[c + 128]);
    }
}

__global__ void k_bnfinal(const float* __restrict__ S1, const float* __restrict__ S2,
                          const float* __restrict__ g, const float* __restrict__ be,
                          float* __restrict__ scale, float* __restrict__ shift,
                          float invN) {
    int c = threadIdx.x;
    if (c >= 128) return;
    float mu = S1[c] * invN;
    float var = S2[c] * invN - mu * mu;
    float sc = g[c] * rsqrtf(var + 1e-5f);
    scale[c] = sc;
    shift[c] = fmaf(-mu, sc, be[c]);
}

// ---------- per-graph histogram of batch ----------
__global__ __launch_bounds__(256) void k_hist(const int* __restrict__ batch, int N,
                                              int* __restrict__ gcnt) {
    __shared__ int h[64];
    if (threadIdx.x < 64) h[threadIdx.x] = 0;
    __syncthreads();
    for (int i = blockIdx.x * 256 + threadIdx.x; i < N; i += gridDim.x * 256)
        atomicAdd(&h[batch[i]], 1);
    __syncthreads();
    if (threadIdx.x < 64 && h[threadIdx.x]) atomicAdd(&gcnt[threadIdx.x], h[threadIdx.x]);
}

// ---------- pool: pooled[g] += relu(bn2(agg2[r])) for r in graph g (batch sorted) ----------
__global__ __launch_bounds__(256) void k_pool(const float* __restrict__ A,
                                              const float* __restrict__ scale,
                                              const float* __restrict__ shift,
                                              const int* __restrict__ batch, int N,
                                              int rpb, float* __restrict__ pooled) {
    int c = threadIdx.x & 127;
    int rh = threadIdx.x >> 7;
    int r0 = blockIdx.x * rpb;
    int r1 = min(r0 + rpb, N);
    float sc = scale[c], sh = shift[c];
    float acc = 0.f; int cur = -1;
    for (int r = r0 + rh; r < r1; r += 2) {
        int g = batch[r];
        if (g != cur) {
            if (cur >= 0) atomicAdd(&pooled[cur * 128 + c], acc);
            acc = 0.f; cur = g;
        }
        float v = fmaf(A[(size_t)r * 128 + c], sc, sh);
        acc += fmaxf(v, 0.f);
    }
    if (cur >= 0) atomicAdd(&pooled[cur * 128 + c], acc);
}

// ---------- FC: out[g][o] = (pooled[g]/cnt[g]) @ Wfc + bfc ----------
__global__ __launch_bounds__(256) void k_fc(const float* __restrict__ pooled,
                                            const int* __restrict__ gcnt,
                                            const float* __restrict__ Wfc,
                                            const float* __restrict__ bfc,
                                            float* __restrict__ out) {
    int idx = blockIdx.x * 256 + threadIdx.x;
    if (idx >= 64 * 32) return;
    int g = idx >> 5, o = idx & 31;
    float inv = 1.f / fmaxf((float)gcnt[g], 1.f);
    float acc = bfc[o];
    for (int k = 0; k < 128; ++k)
        acc = fmaf(pooled[g * 128 + k] * inv, Wfc[k * 32 + o], acc);
    out[idx] = acc;
}

extern "C" void kernel_launch(void* const* d_in, const int* in_sizes, int n_in,
                              void* d_out, int out_size, void* d_ws, size_t ws_size,
                              hipStream_t stream) {
    const float* x    = (const float*)d_in[0];
    const int*  eidx  = (const int*)d_in[1];
    const int*  batch = (const int*)d_in[2];
    const float* W0 = (const float*)d_in[3];
    const float* b0 = (const float*)d_in[4];
    const float* g0 = (const float*)d_in[5];
    const float* be0 = (const float*)d_in[6];
    const float* W1 = (const float*)d_in[7];
    const float* b1 = (const float*)d_in[8];
    const float* g1 = (const float*)d_in[9];
    const float* be1 = (const float*)d_in[10];
    const float* Wfc = (const float*)d_in[11];
    const float* bfc = (const float*)d_in[12];
    float* out = (float*)d_out;

    const int N = in_sizes[0] / 128;
    const int E = in_sizes[1] / 2;
    const int* esrc = eidx;
    const int* edst = eidx + E;

    // ---- workspace carve-up ----
    char* base = (char*)d_ws;
    size_t off = 0;
    auto take = [&](size_t bytes) -> char* {
        char* p = base + off;
        off = (off + bytes + 255) & ~(size_t)255;
        return p;
    };
    unsigned short* hA = (unsigned short*)take((size_t)N * 128 * 2); // bf16 h buffer
    float* B      = (float*)take((size_t)N * 128 * 4);               // fp32 agg buffer
    int*   csr_s  = (int*)take((size_t)E * 4);
    float* csr_n  = (float*)take((size_t)E * 4);
    int*   rowptr = (int*)take((size_t)N * 4);
    char*  zeroA0 = base + off;
    int*   deg    = (int*)take((size_t)N * 4);
    int*   fill   = (int*)take((size_t)N * 4);
    size_t zeroA_bytes = (size_t)((base + off) - zeroA0);
    float* dinv   = (float*)take((size_t)N * 4);
    int*   part   = (int*)take(1024 * 4);
    char*  zeroB0 = base + off;
    float* S1a = (float*)take(128 * 4);
    float* S2a = (float*)take(128 * 4);
    float* S1b = (float*)take(128 * 4);
    float* S2b = (float*)take(128 * 4);
    float* pooled = (float*)take(64 * 128 * 4);
    int*   gcnt   = (int*)take(64 * 4);
    size_t zeroB_bytes = (size_t)((base + off) - zeroB0);
    float* scale1 = (float*)take(128 * 4);
    float* shift1 = (float*)take(128 * 4);
    float* scale2 = (float*)take(128 * 4);
    float* shift2 = (float*)take(128 * 4);
    (void)ws_size; (void)n_in; (void)out_size;

    hipMemsetAsync(zeroA0, 0, zeroA_bytes, stream);
    hipMemsetAsync(zeroB0, 0, zeroB_bytes, stream);

    const int nbE = (E + 255) / 256;
    const int nbScan = (N + 1023) / 1024;

    // graph structure (per call — ws is re-poisoned every launch)
    k_deg<<<nbE, 256, 0, stream>>>(edst, E, deg);
    k_dinv<<<(N + 255) / 256, 256, 0, stream>>>(deg, N, dinv);
    k_scan_part<<<nbScan, 256, 0, stream>>>(deg, N, part);
    k_scan_mid<<<1, 64, 0, stream>>>(part, nbScan);
    k_scan_final<<<nbScan, 256, 0, stream>>>(deg, N, part, rowptr);
    k_fill<<<nbE, 256, 0, stream>>>(esrc, edst, E, rowptr, fill, dinv, csr_s, csr_n);

    const int gGemm = (N + 63) / 64;
    const int gAgg  = (N + 3) / 4;
    const float invN = 1.0f / (float)N;

    // layer 1
    k_gemm<<<gGemm, 256, 0, stream>>>(x, W0, scale1, shift1, hA, N, 0);
    k_agg<<<gAgg, 256, 0, stream>>>(hA, rowptr, deg, csr_s, csr_n, dinv, b0, B, N);
    k_stats<<<512, 256, 0, stream>>>(B, N, S1a, S2a);
    k_bnfinal<<<1, 128, 0, stream>>>(S1a, S2a, g0, be0, scale1, shift1, invN);

    // layer 2 (BN1+ReLU fused into GEMM2's input staging)
    k_gemm<<<gGemm, 256, 0, stream>>>(B, W1, scale1, shift1, hA, N, 1);
    k_agg<<<gAgg, 256, 0, stream>>>(hA, rowptr, deg, csr_s, csr_n, dinv, b1, B, N);
    k_stats<<<512, 256, 0, stream>>>(B, N, S1b, S2b);
    k_bnfinal<<<1, 128, 0, stream>>>(S1b, S2b, g1, be1, scale2, shift2, invN);

    // pool (BN2+ReLU fused) + FC
    k_hist<<<256, 256, 0, stream>>>(batch, N, gcnt);
    const int rpb = (N + 511) / 512;
    k_pool<<<(N + rpb - 1) / rpb, 256, 0, stream>>>(B, scale2, shift2, batch, N, rpb, pooled);
    k_fc<<<8, 256, 0, stream>>>(pooled, gcnt, Wfc, bfc, out);
}

// Round 2
// 663.937 us; speedup vs baseline: 1.0671x; 1.0671x over previous
//
#include <hip/hip_runtime.h>

// ---------- bf16 helpers ----------
__device__ __forceinline__ unsigned short f2bf(float f) {
    unsigned u = __float_as_uint(f);
    u += 0x7fffu + ((u >> 16) & 1u);   // round-to-nearest-even
    return (unsigned short)(u >> 16);
}
__device__ __forceinline__ float bf2f(unsigned short b) {
    return __uint_as_float((unsigned)b << 16);
}
__device__ __forceinline__ float bflo(unsigned u) { return __uint_as_float(u << 16); }
__device__ __forceinline__ float bfhi(unsigned u) { return __uint_as_float(u & 0xffff0000u); }

// ---------- degree count ----------
__global__ __launch_bounds__(256) void k_deg(const int* __restrict__ dst, int E,
                                             int* __restrict__ deg) {
    int i = blockIdx.x * 256 + threadIdx.x;
    if (i < E) atomicAdd(&deg[dst[i]], 1);
}

// ---------- dinv = rsqrt(deg + 1 selfloop) ----------
__global__ __launch_bounds__(256) void k_dinv(const int* __restrict__ deg, int N,
                                              float* __restrict__ dinv) {
    int i = blockIdx.x * 256 + threadIdx.x;
    if (i < N) dinv[i] = rsqrtf((float)(deg[i] + 1));
}

// ---------- 3-kernel exclusive scan of deg -> rowptr (1024 elems / block) ----------
__global__ __launch_bounds__(256) void k_scan_part(const int* __restrict__ deg, int N,
                                                   int* __restrict__ part) {
    int base = blockIdx.x * 1024 + threadIdx.x * 4;
    int s = 0;
#pragma unroll
    for (int i = 0; i < 4; ++i) { int idx = base + i; if (idx < N) s += deg[idx]; }
    __shared__ int red[256];
    red[threadIdx.x] = s; __syncthreads();
    for (int off = 128; off > 0; off >>= 1) {
        if (threadIdx.x < off) red[threadIdx.x] += red[threadIdx.x + off];
        __syncthreads();
    }
    if (threadIdx.x == 0) part[blockIdx.x] = red[0];
}
__global__ void k_scan_mid(int* part, int nb) {
    if (threadIdx.x == 0 && blockIdx.x == 0) {
        int run = 0;
        for (int i = 0; i < nb; ++i) { int t = part[i]; part[i] = run; run += t; }
    }
}
__global__ __launch_bounds__(256) void k_scan_final(const int* __restrict__ deg, int N,
                                                    const int* __restrict__ part,
                                                    int* __restrict__ rowptr) {
    int t = threadIdx.x;
    int base = blockIdx.x * 1024 + t * 4;
    int v[4]; int s = 0;
#pragma unroll
    for (int i = 0; i < 4; ++i) { int idx = base + i; v[i] = (idx < N) ? deg[idx] : 0; s += v[i]; }
    __shared__ int sc[256];
    sc[t] = s; __syncthreads();
    for (int off = 1; off < 256; off <<= 1) {
        int x = (t >= off) ? sc[t - off] : 0;
        __syncthreads();
        sc[t] += x;
        __syncthreads();
    }
    int excl = sc[t] - s + part[blockIdx.x];
#pragma unroll
    for (int i = 0; i < 4; ++i) {
        int idx = base + i;
        if (idx < N) { rowptr[idx] = excl; excl += v[i]; }
    }
}

// ---------- CSR fill: one random atomic + one 8B scattered store per edge ----------
__global__ __launch_bounds__(256) void k_fill(const int* __restrict__ src,
                                              const int* __restrict__ dst, int E,
                                              int* __restrict__ cursor,
                                              const float* __restrict__ dinv,
                                              int2* __restrict__ csr) {
    int i = blockIdx.x * 256 + threadIdx.x;
    if (i >= E) return;
    int s = src[i], d = dst[i];
    int pos = atomicAdd(&cursor[d], 1);
    csr[pos] = make_int2(s, __float_as_int(dinv[s] * dinv[d]));
}

// ---------- GEMM: H(bf16) = act(X) @ W ; act = optional BN(scale,shift)+ReLU ----------
__global__ __launch_bounds__(256) void k_gemm(const float* __restrict__ X,
                                              const float* __restrict__ Wg,
                                              const float* __restrict__ scale,
                                              const float* __restrict__ shift,
                                              unsigned short* __restrict__ Hout,
                                              int N, int applyBN) {
    __shared__ unsigned short sW[128 * 128]; // 32 KB
    __shared__ float sX[64 * 128];           // 32 KB
    const int tid = threadIdx.x;
    const int rowBase = blockIdx.x * 64;

    for (int i = tid * 4; i < 128 * 128; i += 1024) {
        float4 w4 = *(const float4*)&Wg[i];
        ushort4 p;
        p.x = f2bf(w4.x); p.y = f2bf(w4.y); p.z = f2bf(w4.z); p.w = f2bf(w4.w);
        *(ushort4*)&sW[i] = p;
    }
    for (int j = 0; j < 8; ++j) {
        int f4 = tid + 256 * j;
        int r = f4 >> 5;
        int k4 = (f4 & 31) * 4;
        int gr = rowBase + r;
        float4 v = make_float4(0.f, 0.f, 0.f, 0.f);
        if (gr < N) v = *(const float4*)&X[(size_t)gr * 128 + k4];
        if (applyBN) {
            v.x = fmaxf(fmaf(v.x, scale[k4 + 0], shift[k4 + 0]), 0.f);
            v.y = fmaxf(fmaf(v.y, scale[k4 + 1], shift[k4 + 1]), 0.f);
            v.z = fmaxf(fmaf(v.z, scale[k4 + 2], shift[k4 + 2]), 0.f);
            v.w = fmaxf(fmaf(v.w, scale[k4 + 3], shift[k4 + 3]), 0.f);
        }
        *(float4*)&sX[r * 128 + k4] = v;
    }
    __syncthreads();

    const int cg = tid & 31, rg = tid >> 5;
    const int c0 = cg * 4;
    const int r0 = rg * 8;
    float acc[8][4] = {};
#pragma unroll 4
    for (int k = 0; k < 128; ++k) {
        ushort4 wv = *(const ushort4*)&sW[k * 128 + c0];
        float w0 = bf2f(wv.x), w1 = bf2f(wv.y), w2 = bf2f(wv.z), w3 = bf2f(wv.w);
#pragma unroll
        for (int i = 0; i < 8; ++i) {
            float xv = sX[(r0 + i) * 128 + k];
            acc[i][0] = fmaf(xv, w0, acc[i][0]);
            acc[i][1] = fmaf(xv, w1, acc[i][1]);
            acc[i][2] = fmaf(xv, w2, acc[i][2]);
            acc[i][3] = fmaf(xv, w3, acc[i][3]);
        }
    }
#pragma unroll
    for (int i = 0; i < 8; ++i) {
        int gr = rowBase + r0 + i;
        if (gr < N) {
            ushort4 p;
            p.x = f2bf(acc[i][0]); p.y = f2bf(acc[i][1]);
            p.z = f2bf(acc[i][2]); p.w = f2bf(acc[i][3]);
            *(ushort4*)&Hout[(size_t)gr * 128 + c0] = p;
        }
    }
}

// ---------- aggregation: one wave per node, clamp-unroll-4, pipelined csr prefetch ----------
__global__ __launch_bounds__(256) void k_agg(const unsigned short* __restrict__ H,
                                             const int* __restrict__ rowptr,
                                             const int* __restrict__ deg,
                                             const int2* __restrict__ csr,
                                             const float* __restrict__ dinv,
                                             const float* __restrict__ bias,
                                             float* __restrict__ out, int N) {
    int wave = threadIdx.x >> 6;
    int lane = threadIdx.x & 63;
    int node = blockIdx.x * 4 + wave;
    if (node >= N) return;
    const unsigned* Hu = (const unsigned*)H;
    int start = rowptr[node];
    int cnt = deg[node];
    int end = start + cnt;
    float a0 = 0.f, a1 = 0.f;

    if (cnt > 0) {
        int last = end - 1;
        int2 e0 = csr[start];
        int2 e1 = csr[min(start + 1, last)];
        int2 e2 = csr[min(start + 2, last)];
        int2 e3 = csr[min(start + 3, last)];
        int j = start;
        while (j < end) {
            // issue 4 gathers (independent chains)
            unsigned u0 = Hu[(size_t)e0.x * 64 + lane];
            unsigned u1 = Hu[(size_t)e1.x * 64 + lane];
            unsigned u2 = Hu[(size_t)e2.x * 64 + lane];
            unsigned u3 = Hu[(size_t)e3.x * 64 + lane];
            float w0 = __int_as_float(e0.y);
            float w1 = (j + 1 < end) ? __int_as_float(e1.y) : 0.f;
            float w2 = (j + 2 < end) ? __int_as_float(e2.y) : 0.f;
            float w3 = (j + 3 < end) ? __int_as_float(e3.y) : 0.f;
            int jn = j + 4;
            if (jn < end) {  // prefetch next csr quad while gathers are in flight
                e0 = csr[jn];
                e1 = csr[min(jn + 1, last)];
                e2 = csr[min(jn + 2, last)];
                e3 = csr[min(jn + 3, last)];
            }
            a0 = fmaf(w0, bflo(u0), a0); a1 = fmaf(w0, bfhi(u0), a1);
            a0 = fmaf(w1, bflo(u1), a0); a1 = fmaf(w1, bfhi(u1), a1);
            a0 = fmaf(w2, bflo(u2), a0); a1 = fmaf(w2, bfhi(u2), a1);
            a0 = fmaf(w3, bflo(u3), a0); a1 = fmaf(w3, bfhi(u3), a1);
            j = jn;
        }
    }
    { // self loop
        float dn = dinv[node];
        float w = dn * dn;
        unsigned u = Hu[(size_t)node * 64 + lane];
        a0 = fmaf(w, bflo(u), a0);
        a1 = fmaf(w, bfhi(u), a1);
    }
    float2 bv = ((const float2*)bias)[lane];
    a0 += bv.x;
    a1 += bv.y;
    ((float2*)out)[(size_t)node * 64 + lane] = make_float2(a0, a1);
}

// ---------- BN column stats ----------
__global__ __launch_bounds__(256) void k_stats(const float* __restrict__ A, int N,
                                               float* __restrict__ S1,
                                               float* __restrict__ S2) {
    int c = threadIdx.x & 127;
    int rh = threadIdx.x >> 7;
    float s1 = 0.f, s2 = 0.f;
    for (int r = blockIdx.x * 2 + rh; r < N; r += gridDim.x * 2) {
        float v = A[(size_t)r * 128 + c];
        s1 += v;
        s2 = fmaf(v, v, s2);
    }
    __shared__ float l1[256], l2[256];
    l1[threadIdx.x] = s1; l2[threadIdx.x] = s2;
    __syncthreads();
    if (rh == 0) {
        atomicAdd(&S1[c], s1 + l1[c + 128]);
        atomicAdd(&S2[c], s2 + l2[c + 128]);
    }
}

__global__ void k_bnfinal(const float* __restrict__ S1, const float* __restrict__ S2,
                          const float* __restrict__ g, const float* __restrict__ be,
                          float* __restrict__ scale, float* __restrict__ shift,
                          float invN) {
    int c = threadIdx.x;
    if (c >= 128) return;
    float mu = S1[c] * invN;
    float var = S2[c] * invN - mu * mu;
    float sc = g[c] * rsqrtf(var + 1e-5f);
    scale[c] = sc;
    shift[c] = fmaf(-mu, sc, be[c]);
}

// ---------- per-graph histogram of batch ----------
__global__ __launch_bounds__(256) void k_hist(const int* __restrict__ batch, int N,
                                              int* __restrict__ gcnt) {
    __shared__ int h[64];
    if (threadIdx.x < 64) h[threadIdx.x] = 0;
    __syncthreads();
    for (int i = blockIdx.x * 256 + threadIdx.x; i < N; i += gridDim.x * 256)
        atomicAdd(&h[batch[i]], 1);
    __syncthreads();
    if (threadIdx.x < 64 && h[threadIdx.x]) atomicAdd(&gcnt[threadIdx.x], h[threadIdx.x]);
}

// ---------- pool ----------
__global__ __launch_bounds__(256) void k_pool(const float* __restrict__ A,
                                              const float* __restrict__ scale,
                                              const float* __restrict__ shift,
                                              const int* __restrict__ batch, int N,
                                              int rpb, float* __restrict__ pooled) {
    int c = threadIdx.x & 127;
    int rh = threadIdx.x >> 7;
    int r0 = blockIdx.x * rpb;
    int r1 = min(r0 + rpb, N);
    float sc = scale[c], sh = shift[c];
    float acc = 0.f; int cur = -1;
    for (int r = r0 + rh; r < r1; r += 2) {
        int g = batch[r];
        if (g != cur) {
            if (cur >= 0) atomicAdd(&pooled[cur * 128 + c], acc);
            acc = 0.f; cur = g;
        }
        float v = fmaf(A[(size_t)r * 128 + c], sc, sh);
        acc += fmaxf(v, 0.f);
    }
    if (cur >= 0) atomicAdd(&pooled[cur * 128 + c], acc);
}

// ---------- FC ----------
__global__ __launch_bounds__(256) void k_fc(const float* __restrict__ pooled,
                                            const int* __restrict__ gcnt,
                                            const float* __restrict__ Wfc,
                                            const float* __restrict__ bfc,
                                            float* __restrict__ out) {
    int idx = blockIdx.x * 256 + threadIdx.x;
    if (idx >= 64 * 32) return;
    int g = idx >> 5, o = idx & 31;
    float inv = 1.f / fmaxf((float)gcnt[g], 1.f);
    float acc = bfc[o];
    for (int k = 0; k < 128; ++k)
        acc = fmaf(pooled[g * 128 + k] * inv, Wfc[k * 32 + o], acc);
    out[idx] = acc;
}

extern "C" void kernel_launch(void* const* d_in, const int* in_sizes, int n_in,
                              void* d_out, int out_size, void* d_ws, size_t ws_size,
                              hipStream_t stream) {
    const float* x    = (const float*)d_in[0];
    const int*  eidx  = (const int*)d_in[1];
    const int*  batch = (const int*)d_in[2];
    const float* W0 = (const float*)d_in[3];
    const float* b0 = (const float*)d_in[4];
    const float* g0 = (const float*)d_in[5];
    const float* be0 = (const float*)d_in[6];
    const float* W1 = (const float*)d_in[7];
    const float* b1 = (const float*)d_in[8];
    const float* g1 = (const float*)d_in[9];
    const float* be1 = (const float*)d_in[10];
    const float* Wfc = (const float*)d_in[11];
    const float* bfc = (const float*)d_in[12];
    float* out = (float*)d_out;

    const int N = in_sizes[0] / 128;
    const int E = in_sizes[1] / 2;
    const int* esrc = eidx;
    const int* edst = eidx + E;

    // ---- workspace carve-up ----
    char* base = (char*)d_ws;
    size_t off = 0;
    auto take = [&](size_t bytes) -> char* {
        char* p = base + off;
        off = (off + bytes + 255) & ~(size_t)255;
        return p;
    };
    unsigned short* hA = (unsigned short*)take((size_t)N * 128 * 2);
    float* B      = (float*)take((size_t)N * 128 * 4);
    int2*  csr    = (int2*)take((size_t)E * 8);
    int*   rowptr = (int*)take((size_t)N * 4);
    int*   cursor = (int*)take((size_t)N * 4);
    char*  zeroA0 = base + off;
    int*   deg    = (int*)take((size_t)N * 4);
    size_t zeroA_bytes = (size_t)((base + off) - zeroA0);
    float* dinv   = (float*)take((size_t)N * 4);
    int*   part   = (int*)take(1024 * 4);
    char*  zeroB0 = base + off;
    float* S1a = (float*)take(128 * 4);
    float* S2a = (float*)take(128 * 4);
    float* S1b = (float*)take(128 * 4);
    float* S2b = (float*)take(128 * 4);
    float* pooled = (float*)take(64 * 128 * 4);
    int*   gcnt   = (int*)take(64 * 4);
    size_t zeroB_bytes = (size_t)((base + off) - zeroB0);
    float* scale1 = (float*)take(128 * 4);
    float* shift1 = (float*)take(128 * 4);
    float* scale2 = (float*)take(128 * 4);
    float* shift2 = (float*)take(128 * 4);
    (void)ws_size; (void)n_in; (void)out_size;

    hipMemsetAsync(zeroA0, 0, zeroA_bytes, stream);
    hipMemsetAsync(zeroB0, 0, zeroB_bytes, stream);

    const int nbE = (E + 255) / 256;
    const int nbScan = (N + 1023) / 1024;

    k_deg<<<nbE, 256, 0, stream>>>(edst, E, deg);
    k_dinv<<<(N + 255) / 256, 256, 0, stream>>>(deg, N, dinv);
    k_scan_part<<<nbScan, 256, 0, stream>>>(deg, N, part);
    k_scan_mid<<<1, 64, 0, stream>>>(part, nbScan);
    k_scan_final<<<nbScan, 256, 0, stream>>>(deg, N, part, rowptr);
    hipMemcpyAsync(cursor, rowptr, (size_t)N * 4, hipMemcpyDeviceToDevice, stream);
    k_fill<<<nbE, 256, 0, stream>>>(esrc, edst, E, cursor, dinv, csr);

    const int gGemm = (N + 63) / 64;
    const int gAgg  = (N + 3) / 4;
    const float invN = 1.0f / (float)N;

    // layer 1
    k_gemm<<<gGemm, 256, 0, stream>>>(x, W0, scale1, shift1, hA, N, 0);
    k_agg<<<gAgg, 256, 0, stream>>>(hA, rowptr, deg, csr, dinv, b0, B, N);
    k_stats<<<512, 256, 0, stream>>>(B, N, S1a, S2a);
    k_bnfinal<<<1, 128, 0, stream>>>(S1a, S2a, g0, be0, scale1, shift1, invN);

    // layer 2 (BN1+ReLU fused into GEMM2's input staging)
    k_gemm<<<gGemm, 256, 0, stream>>>(B, W1, scale1, shift1, hA, N, 1);
    k_agg<<<gAgg, 256, 0, stream>>>(hA, rowptr, deg, csr, dinv, b1, B, N);
    k_stats<<<512, 256, 0, stream>>>(B, N, S1b, S2b);
    k_bnfinal<<<1, 128, 0, stream>>>(S1b, S2b, g1, be1, scale2, shift2, invN);

    // pool (BN2+ReLU fused) + FC
    k_hist<<<256, 256, 0, stream>>>(batch, N, gcnt);
    const int rpb = (N + 511) / 512;
    k_pool<<<(N + rpb - 1) / rpb, 256, 0, stream>>>(B, scale2, shift2, batch, N, rpb, pooled);
    k_fc<<<8, 256, 0, stream>>>(pooled, gcnt, Wfc, bfc, out);
}